// Round 7
// baseline (18.658 us; speedup 1.0000x reference)
//
#include <hip/hip_runtime.h>
#include <math.h>

// Problem constants (from reference)
#define BB 16
#define CC 3
#define OO 32
#define HH 128
#define WW 128
#define OH 124
#define OW 124
#define NPIX (OH * OW)          // 15376
#define NG   (NPIX / 4)         // 3844 4-pixel groups
#define GW   (OW / 4)           // 31 groups per output row
#define KF 25.0f

#define TPB  512
#define NBLK (NG / 4)           // 961 blocks, 16 pixels each

#if defined(__has_builtin)
#if __has_builtin(__builtin_amdgcn_sqrtf)
#define FSQRT(x) __builtin_amdgcn_sqrtf(x)
#else
#define FSQRT(x) sqrtf(x)
#endif
#else
#define FSQRT(x) sqrtf(x)
#endif

// ---------------------------------------------------------------------------
// ONE kernel, block owns 16 pixels x all (16 b, 32 o). 512 threads:
//   t = b*32 + og*4 + p4   (b: 0..15, og: 0..7 -> 4 o each, p4: 0..3)
// Phase 0: window sums from x -> LDS              (192 threads)
// Phase 1: dist partials, dist[4][4] in VGPRs     (512 threads)
// Phase 2: per-pixel unbiased 1/std (double)      (64 + 16 threads)
// Phase 3: out = exp(-0.5 (dist*invstd)^2)        (512 threads, f4 stores)
// Block->pixel mapping is XCD-swizzled (bijective, 961 = 8*120+1) so
// same-XCD blocks own contiguous pixel spans -> full-line L2 writebacks.
// ---------------------------------------------------------------------------
__global__ __launch_bounds__(TPB, 4)
void fused_one(const float* __restrict__ x,
               const float* __restrict__ wgt,
               float* __restrict__ out) {
    __shared__ float  sS1[BB * CC][16];    // 3 KB
    __shared__ float  sS2[BB * CC][16];    // 3 KB
    __shared__ float  sPS[BB * 8][17];     // 8.5 KB (pad 17: no bank conflict)
    __shared__ float  sPQ[BB * 8][17];     // 8.5 KB
    __shared__ float  sW[OO * CC];
    __shared__ float  sInv[16];
    __shared__ double sRm[16][4];
    __shared__ double sRq[16][4];

    const int t = threadIdx.x;

    // Bijective XCD swizzle: orig%8 = XCD (round-robin dispatch); give each
    // XCD a contiguous chunk range. 961 blocks: q=120, r=1.
    {
    }
    const int orig = blockIdx.x;
    const int xcd  = orig & 7;
    const int loc  = orig >> 3;
    const int chunk = ((xcd < 1) ? xcd * 121 : 121 + (xcd - 1) * 120) + loc;
    const int g0 = chunk * 4;              // first pix4 group of this block

    // ---------------- Phase 0: weights + window sums ----------------
    if (t >= 192 && t < 192 + OO * CC) sW[t - 192] = wgt[t - 192];
    if (t < BB * CC * 4) {                 // 192 active
        int bc = t >> 2;                   // 0..47
        int p4 = t & 3;                    // 0..3
        int g  = g0 + p4;
        int i  = g / GW;
        int j0 = (g % GW) * 4;
        const float* img = x + (size_t)bc * (HH * WW);
        float S1[4] = {0, 0, 0, 0}, S2[4] = {0, 0, 0, 0};
#pragma unroll
        for (int di = 0; di < 5; ++di) {
            const float4* rp = reinterpret_cast<const float4*>(img + (i + di) * WW + j0);
            float4 lo = rp[0], hi = rp[1];
            float v[8] = {lo.x, lo.y, lo.z, lo.w, hi.x, hi.y, hi.z, hi.w};
            float q[8];
#pragma unroll
            for (int k = 0; k < 8; ++k) q[k] = v[k] * v[k];
            float r  = v[0] + v[1] + v[2] + v[3] + v[4];
            float rq = q[0] + q[1] + q[2] + q[3] + q[4];
            S1[0] += r;  S2[0] += rq;
#pragma unroll
            for (int u = 1; u < 4; ++u) {
                r  += v[u + 4] - v[u - 1];
                rq += q[u + 4] - q[u - 1];
                S1[u] += r;  S2[u] += rq;
            }
        }
#pragma unroll
        for (int u = 0; u < 4; ++u) {
            sS1[bc][p4 * 4 + u] = S1[u];
            sS2[bc][p4 * 4 + u] = S2[u];
        }
    }
    __syncthreads();

    // ---------------- Phase 1: dist partials (dist stays in registers) ----
    const int b  = t >> 5;        // 0..15
    const int og = (t >> 2) & 7;  // 0..7  (4 o's each)
    const int p4 = t & 3;         // 0..3  (4 pixels each)

    float S1c[CC][4], S2c[CC][4];
#pragma unroll
    for (int c = 0; c < CC; ++c) {
#pragma unroll
        for (int u = 0; u < 4; ++u) {
            S1c[c][u] = sS1[b * CC + c][p4 * 4 + u];
            S2c[c][u] = sS2[b * CC + c][p4 * 4 + u];
        }
    }

    float dist[4][4];
    float sum[4] = {0, 0, 0, 0}, sq[4] = {0, 0, 0, 0};
#pragma unroll
    for (int oo = 0; oo < 4; ++oo) {
        int o = og * 4 + oo;
        float d[4] = {0, 0, 0, 0};
#pragma unroll
        for (int c = 0; c < CC; ++c) {
            float w  = sW[o * CC + c];
            float tw = 2.0f * w;
            float kw = KF * w * w;
#pragma unroll
            for (int u = 0; u < 4; ++u) {
                float inner = S2c[c][u] - tw * S1c[c][u] + kw;
                d[u] += FSQRT(fmaxf(inner, 0.0f));
            }
        }
#pragma unroll
        for (int u = 0; u < 4; ++u) {
            dist[oo][u] = d[u];
            sum[u] += d[u];
            sq[u]  += d[u] * d[u];
        }
    }
    {
        const int row = t >> 2;   // == b*8+og
#pragma unroll
        for (int u = 0; u < 4; ++u) {
            sPS[row][p4 * 4 + u] = sum[u];
            sPQ[row][p4 * 4 + u] = sq[u];
        }
    }
    __syncthreads();

    // ---------------- Phase 2: per-pixel 1/std (double) ----------------
    if (t < 64) {
        int pix = t >> 2;   // 0..15
        int seg = t & 3;    // 0..3, 32 rows each
        double sm = 0.0, sQ = 0.0;
#pragma unroll
        for (int k = 0; k < 32; ++k) {
            sm += (double)sPS[seg * 32 + k][pix];
            sQ += (double)sPQ[seg * 32 + k][pix];
        }
        sRm[pix][seg] = sm;
        sRq[pix][seg] = sQ;
    }
    __syncthreads();
    if (t < 16) {
        double sm = sRm[t][0] + sRm[t][1] + sRm[t][2] + sRm[t][3];
        double sQ = sRq[t][0] + sRq[t][1] + sRq[t][2] + sRq[t][3];
        const double n = (double)(BB * OO);
        double mean = sm / n;
        double var = (sQ - n * mean * mean) / (n - 1.0);
        if (var < 0.0) var = 0.0;
        sInv[t] = (float)(1.0 / sqrt(var));
    }
    __syncthreads();

    // ---------------- Phase 3: output ----------------
    float isd[4];
#pragma unroll
    for (int u = 0; u < 4; ++u) isd[u] = sInv[p4 * 4 + u];
    const size_t pixbase = (size_t)(g0 + p4) * 4;

#pragma unroll
    for (int oo = 0; oo < 4; ++oo) {
        int o = og * 4 + oo;
        float4 r;
        float z0 = dist[oo][0] * isd[0]; r.x = __expf(-0.5f * z0 * z0);
        float z1 = dist[oo][1] * isd[1]; r.y = __expf(-0.5f * z1 * z1);
        float z2 = dist[oo][2] * isd[2]; r.z = __expf(-0.5f * z2 * z2);
        float z3 = dist[oo][3] * isd[3]; r.w = __expf(-0.5f * z3 * z3);
        *reinterpret_cast<float4*>(&out[(size_t)(b * OO + o) * NPIX + pixbase]) = r;
    }
}

// ---------------------------------------------------------------------------
extern "C" void kernel_launch(void* const* d_in, const int* in_sizes, int n_in,
                              void* d_out, int out_size, void* d_ws, size_t ws_size,
                              hipStream_t stream) {
    const float* x   = (const float*)d_in[0];   // (16,3,128,128)
    const float* wgt = (const float*)d_in[1];   // (32,3)
    float* out = (float*)d_out;                 // (16,32,124,124)

    fused_one<<<NBLK, TPB, 0, stream>>>(x, wgt, out);
}

// Round 10
// 17.607 us; speedup vs baseline: 1.0597x; 1.0597x over previous
//
#include <hip/hip_runtime.h>
#include <math.h>

// Problem constants (from reference)
#define BB 16
#define CC 3
#define OO 32
#define HH 128
#define WW 128
#define OH 124
#define OW 124
#define NPIX (OH * OW)          // 15376
#define NG   (NPIX / 4)         // 3844 4-pixel groups
#define GW   (OW / 4)           // 31 groups per output row
#define KF 25.0f

#define TPB  256
#define NBLK (NG / 4)           // 961 blocks, 16 pixels each (whole grid co-resident)

typedef float vfloat4 __attribute__((ext_vector_type(4)));  // native vec for nt-store

#if defined(__has_builtin)
#if __has_builtin(__builtin_amdgcn_sqrtf)
#define FSQRT(x) __builtin_amdgcn_sqrtf(x)
#else
#define FSQRT(x) sqrtf(x)
#endif
#else
#define FSQRT(x) sqrtf(x)
#endif

// ---------------------------------------------------------------------------
// ONE kernel (R6 structure). Block owns 16 pixels x all (16 b, 32 o).
//   t = b*16 + og*4 + p4   (b: 0..15, og: 0..3 -> 8 o each, p4: 0..3)
// Phase 0: window sums from x -> LDS           (192 threads; t<96 also preload W)
// Phase 1: dist partials, dist[8][4] in VGPRs  (256 threads)
// Phase 2: per-pixel unbiased 1/std (double)   (64 + 16 threads)
// Phase 3: out = exp(-0.5 (dist*invstd)^2)     (256 threads, nt float4 stores)
// Block->pixel mapping XCD-swizzled (bijective, 961 = 121 + 7*120) so each
// XCD touches a contiguous pixel span -> only ~1/8 of x rows fetched per XCD.
// All LDS rows padded to 17 floats (bank-conflict-free per m136 2-way rule).
// ---------------------------------------------------------------------------
__global__ __launch_bounds__(TPB, 4)
void fused_one(const float* __restrict__ x,
               const float* __restrict__ wgt,
               float* __restrict__ out) {
    __shared__ float  sS1[BB * CC][17];    // 3.3 KB
    __shared__ float  sS2[BB * CC][17];    // 3.3 KB
    __shared__ float  sPS[BB * 4][17];     // 4.4 KB
    __shared__ float  sPQ[BB * 4][17];     // 4.4 KB
    __shared__ float  sW[OO * CC];
    __shared__ float  sInv[16];
    __shared__ double sRm[16][4];
    __shared__ double sRq[16][4];

    const int t = threadIdx.x;

    // Bijective XCD swizzle: round-robin dispatch puts orig%8 on XCD orig%8;
    // give each XCD a contiguous chunk range. 961 = 121 + 7*120.
    const int orig = blockIdx.x;
    const int xcd  = orig & 7;
    const int loc  = orig >> 3;
    const int chunk = ((xcd == 0) ? 0 : 121 + (xcd - 1) * 120) + loc;
    const int g0 = chunk * 4;              // first pix4 group of this block

    // ---------------- Phase 0: weights + window sums ----------------
    if (t < OO * CC) sW[t] = wgt[t];       // 96 weights (t<96; TPB=256!)
    if (t < BB * CC * 4) {                 // 192 active
        int bc = t >> 2;                   // 0..47
        int p4 = t & 3;                    // 0..3
        int g  = g0 + p4;
        int i  = g / GW;
        int j0 = (g % GW) * 4;
        const float* img = x + (size_t)bc * (HH * WW);
        float S1[4] = {0, 0, 0, 0}, S2[4] = {0, 0, 0, 0};
#pragma unroll
        for (int di = 0; di < 5; ++di) {
            const float4* rp = reinterpret_cast<const float4*>(img + (i + di) * WW + j0);
            float4 lo = rp[0], hi = rp[1];
            float v[8] = {lo.x, lo.y, lo.z, lo.w, hi.x, hi.y, hi.z, hi.w};
            float q[8];
#pragma unroll
            for (int k = 0; k < 8; ++k) q[k] = v[k] * v[k];
            float r  = v[0] + v[1] + v[2] + v[3] + v[4];
            float rq = q[0] + q[1] + q[2] + q[3] + q[4];
            S1[0] += r;  S2[0] += rq;
#pragma unroll
            for (int u = 1; u < 4; ++u) {
                r  += v[u + 4] - v[u - 1];
                rq += q[u + 4] - q[u - 1];
                S1[u] += r;  S2[u] += rq;
            }
        }
#pragma unroll
        for (int u = 0; u < 4; ++u) {
            sS1[bc][p4 * 4 + u] = S1[u];
            sS2[bc][p4 * 4 + u] = S2[u];
        }
    }
    __syncthreads();

    // ---------------- Phase 1: dist partials (dist stays in registers) ----
    const int b  = t >> 4;        // 0..15
    const int og = (t >> 2) & 3;  // 0..3  (8 o's each)
    const int p4 = t & 3;         // 0..3  (4 pixels each)

    float S1c[CC][4], S2c[CC][4];
#pragma unroll
    for (int c = 0; c < CC; ++c) {
#pragma unroll
        for (int u = 0; u < 4; ++u) {
            S1c[c][u] = sS1[b * CC + c][p4 * 4 + u];
            S2c[c][u] = sS2[b * CC + c][p4 * 4 + u];
        }
    }

    float dist[8][4];
    float sum[4] = {0, 0, 0, 0}, sq[4] = {0, 0, 0, 0};
#pragma unroll
    for (int oo = 0; oo < 8; ++oo) {
        int o = og * 8 + oo;
        float d[4] = {0, 0, 0, 0};
#pragma unroll
        for (int c = 0; c < CC; ++c) {
            float w  = sW[o * CC + c];
            float tw = 2.0f * w;
            float kw = KF * w * w;
#pragma unroll
            for (int u = 0; u < 4; ++u) {
                float inner = S2c[c][u] - tw * S1c[c][u] + kw;
                d[u] += FSQRT(fmaxf(inner, 0.0f));
            }
        }
#pragma unroll
        for (int u = 0; u < 4; ++u) {
            dist[oo][u] = d[u];
            sum[u] += d[u];
            sq[u]  += d[u] * d[u];
        }
    }
#pragma unroll
    for (int u = 0; u < 4; ++u) {
        sPS[b * 4 + og][p4 * 4 + u] = sum[u];
        sPQ[b * 4 + og][p4 * 4 + u] = sq[u];
    }
    __syncthreads();

    // ---------------- Phase 2: per-pixel 1/std (double) ----------------
    if (t < 64) {
        int pix = t >> 2;   // 0..15
        int seg = t & 3;    // 0..3, 16 rows each
        double sm = 0.0, sQ = 0.0;
#pragma unroll
        for (int k = 0; k < 16; ++k) {
            sm += (double)sPS[seg * 16 + k][pix];
            sQ += (double)sPQ[seg * 16 + k][pix];
        }
        sRm[pix][seg] = sm;
        sRq[pix][seg] = sQ;
    }
    __syncthreads();
    if (t < 16) {
        double sm = sRm[t][0] + sRm[t][1] + sRm[t][2] + sRm[t][3];
        double sQ = sRq[t][0] + sRq[t][1] + sRq[t][2] + sRq[t][3];
        const double n = (double)(BB * OO);
        double mean = sm / n;
        double var = (sQ - n * mean * mean) / (n - 1.0);
        if (var < 0.0) var = 0.0;
        sInv[t] = (float)(1.0 / sqrt(var));
    }
    __syncthreads();

    // ---------------- Phase 3: output (nontemporal streaming stores) ------
    float isd[4];
#pragma unroll
    for (int u = 0; u < 4; ++u) isd[u] = sInv[p4 * 4 + u];
    const size_t pixbase = (size_t)(g0 + p4) * 4;

#pragma unroll
    for (int oo = 0; oo < 8; ++oo) {
        int o = og * 8 + oo;
        vfloat4 r;
        float z0 = dist[oo][0] * isd[0]; r.x = __expf(-0.5f * z0 * z0);
        float z1 = dist[oo][1] * isd[1]; r.y = __expf(-0.5f * z1 * z1);
        float z2 = dist[oo][2] * isd[2]; r.z = __expf(-0.5f * z2 * z2);
        float z3 = dist[oo][3] * isd[3]; r.w = __expf(-0.5f * z3 * z3);
        __builtin_nontemporal_store(r,
            reinterpret_cast<vfloat4*>(&out[(size_t)(b * OO + o) * NPIX + pixbase]));
    }
}

// ---------------------------------------------------------------------------
extern "C" void kernel_launch(void* const* d_in, const int* in_sizes, int n_in,
                              void* d_out, int out_size, void* d_ws, size_t ws_size,
                              hipStream_t stream) {
    const float* x   = (const float*)d_in[0];   // (16,3,128,128)
    const float* wgt = (const float*)d_in[1];   // (32,3)
    float* out = (float*)d_out;                 // (16,32,124,124)

    fused_one<<<NBLK, TPB, 0, stream>>>(x, wgt, out);
}